// Round 11
// baseline (335.980 us; speedup 1.0000x reference)
//
#include <hip/hip_runtime.h>
#include <hip/hip_bf16.h>

typedef __bf16 bf16x8 __attribute__((ext_vector_type(8)));
typedef __bf16 bf16x4v __attribute__((ext_vector_type(4)));
typedef float f32x4 __attribute__((ext_vector_type(4)));
typedef unsigned int u32x4 __attribute__((ext_vector_type(4)));

using bf16 = __hip_bfloat16;

// ---------------- elementwise fp32 -> bf16 ----------------
__global__ __launch_bounds__(256) void k_cvt_bf16(const float* __restrict__ in,
                                                  bf16* __restrict__ out) {
  const int i = (blockIdx.x * 256 + threadIdx.x) * 4;
  float4 v = *reinterpret_cast<const float4*>(in + i);
  out[i + 0] = __float2bfloat16(v.x);
  out[i + 1] = __float2bfloat16(v.y);
  out[i + 2] = __float2bfloat16(v.z);
  out[i + 3] = __float2bfloat16(v.w);
}

// ---------------- weight transpose + convert: wt[n][k] = (bf16)w[k][n] ----------------
__global__ __launch_bounds__(256) void k_transpose_bf16(const float* __restrict__ w,
                                                        bf16* __restrict__ wt,
                                                        int K, int N) {
  __shared__ float t[32][33];
  const int k0 = blockIdx.x * 32, n0 = blockIdx.y * 32;
  const int tx = threadIdx.x & 31, ty = threadIdx.x >> 5;
#pragma unroll
  for (int i = 0; i < 32; i += 8)
    t[ty + i][tx] = w[(size_t)(k0 + ty + i) * N + n0 + tx];
  __syncthreads();
#pragma unroll
  for (int i = 0; i < 32; i += 8)
    wt[(size_t)(n0 + ty + i) * K + k0 + tx] = __float2bfloat16(t[tx][ty + i]);
}

// ---------------- fold grouped-1x1 pw into wr2T sections ----------------
__global__ __launch_bounds__(256) void k_fuse_pw(const float* __restrict__ pw0,
                                                 const float* __restrict__ pw1,
                                                 const float* __restrict__ pw2,
                                                 const float* __restrict__ w2,
                                                 bf16* __restrict__ wr2T) {
  const int g = blockIdx.x;
  const int n0 = blockIdx.y * 64;
  const int i = blockIdx.z;
  const float* __restrict__ pw = (i == 0) ? pw0 : (i == 1) ? pw1 : pw2;
  __shared__ float pwL[32][36];
  {
    const int q = threadIdx.x >> 3, c4 = (threadIdx.x & 7) * 4;
    float4 v = *reinterpret_cast<const float4*>(pw + (size_t)(g * 32 + q) * 32 + c4);
    *reinterpret_cast<float4*>(&pwL[q][c4]) = v;
  }
  __syncthreads();
  const int n = n0 + (threadIdx.x & 63);
  const int ch = threadIdx.x >> 6;
  const int kbase = 768 * (i + 1) + g * 32;
  float acc[8] = {};
  for (int q = 0; q < 32; ++q) {
    const float w2v = w2[(size_t)(kbase + q) * 768 + n];
#pragma unroll
    for (int e = 0; e < 8; ++e) acc[e] += pwL[q][ch * 8 + e] * w2v;
  }
  bf16x8 o;
#pragma unroll
  for (int e = 0; e < 8; ++e) o[e] = (__bf16)acc[e];
  *reinterpret_cast<bf16x8*>(wr2T + (size_t)n * 3072 + kbase + ch * 8) = o;
}

// ---------------- bf16 2D transpose per batch: in [z][R][C] -> out [z][C][R] ----------------
__global__ __launch_bounds__(256) void k_transpose2d(const bf16* __restrict__ in,
                                                     bf16* __restrict__ out,
                                                     int R, int C) {
  __shared__ unsigned short tl[64][65];
  const int c0 = blockIdx.x * 64, r0 = blockIdx.y * 64;
  const size_t zb = (size_t)blockIdx.z * R * C;
  const int tx = threadIdx.x & 63, ty = threadIdx.x >> 6;
  const unsigned short* ip = (const unsigned short*)in + zb;
  unsigned short* op = (unsigned short*)out + zb;
#pragma unroll
  for (int i = 0; i < 64; i += 4)
    tl[ty + i][tx] = ip[(size_t)(r0 + ty + i) * C + c0 + tx];
  __syncthreads();
#pragma unroll
  for (int i = 0; i < 64; i += 4)
    op[(size_t)(c0 + ty + i) * R + r0 + tx] = tl[tx][ty + i];
}

// ---------------- GEMM: C[M,N] = A[M,K] * Bt[N,K]^T  (bf16 in, fp32 acc) ----------------
// Tile BM x BN, BK=64; global_load_lds width-16 staging + 2-phase dbuf prefetch.
// 4 waves in 2x2; per-wave tile (BM/2) x (BN/2). BN=64 -> 32KB LDS -> 5 blocks/CU.
template <int BM, int BN>
__global__ __launch_bounds__(256) void k_gemm_bt(
    const bf16* __restrict__ A0, const bf16* __restrict__ A1,
    const bf16* __restrict__ A2, const bf16* __restrict__ A3,
    const bf16* __restrict__ Bt, bf16* __restrict__ Cb,
    float* __restrict__ Cf, const float* __restrict__ bias,
    int N, int K, int srcK, int split_bk) {
  constexpr int MR = BM / 32;  // acc row-frags per wave
  constexpr int NR = BN / 32;  // acc col-frags per wave
  __shared__ __align__(16) bf16 As[2][BM * 64];
  __shared__ __align__(16) bf16 Bs[2][BN * 64];
  const int tid = threadIdx.x;
  const int lane = tid & 63;
  const int wv = tid >> 6;
  const size_t M0 = (size_t)blockIdx.x * BM;
  const int N0 = blockIdx.y * BN;
  const int wr = (wv >> 1) * (BM / 2), wc = (wv & 1) * (BN / 2);
  const int fr = lane & 15, fo = (lane >> 4) * 8;
  const int lrow = lane >> 3, lcol = (lane & 7) << 3;
  f32x4 acc[MR][NR] = {};

  auto stage = [&](int kt, int buf) {
    const int s = kt / split_bk;
    const bf16* __restrict__ Ak = (s == 0) ? A0 : (s == 1) ? A1 : (s == 2) ? A2 : A3;
    const size_t aofs = (size_t)(kt - s * split_bk) * 64;
    const size_t bofs = (size_t)kt * 64;
#pragma unroll
    for (int ld = 0; ld < BM / 32; ++ld) {
      const int row = wv * (BM / 4) + ld * 8;
      const bf16* ga = Ak + (M0 + row + lrow) * (size_t)srcK + aofs + lcol;
      __builtin_amdgcn_global_load_lds(
          (const __attribute__((address_space(1))) unsigned int*)ga,
          (__attribute__((address_space(3))) unsigned int*)(As[buf] + row * 64),
          16, 0, 0);
    }
#pragma unroll
    for (int ld = 0; ld < BN / 32; ++ld) {
      const int row = wv * (BN / 4) + ld * 8;
      const bf16* gb = Bt + (size_t)(N0 + row + lrow) * K + bofs + lcol;
      __builtin_amdgcn_global_load_lds(
          (const __attribute__((address_space(1))) unsigned int*)gb,
          (__attribute__((address_space(3))) unsigned int*)(Bs[buf] + row * 64),
          16, 0, 0);
    }
  };

  const int nsteps = K >> 6;
  stage(0, 0);
  __syncthreads();
  int cur = 0;
  for (int kt = 0; kt < nsteps; ++kt) {
    if (kt + 1 < nsteps) stage(kt + 1, cur ^ 1);
#pragma unroll
    for (int kk = 0; kk < 64; kk += 32) {
      bf16x8 a[MR], b[NR];
#pragma unroll
      for (int m = 0; m < MR; ++m)
        a[m] = *reinterpret_cast<const bf16x8*>(As[cur] + (wr + m * 16 + fr) * 64 + kk + fo);
#pragma unroll
      for (int n = 0; n < NR; ++n)
        b[n] = *reinterpret_cast<const bf16x8*>(Bs[cur] + (wc + n * 16 + fr) * 64 + kk + fo);
#pragma unroll
      for (int m = 0; m < MR; ++m)
#pragma unroll
        for (int n = 0; n < NR; ++n)
          acc[m][n] = __builtin_amdgcn_mfma_f32_16x16x32_bf16(a[m], b[n], acc[m][n], 0, 0, 0);
    }
    __syncthreads();
    cur ^= 1;
  }

  const int rb = (lane >> 4) * 4;
#pragma unroll
  for (int m = 0; m < MR; ++m) {
#pragma unroll
    for (int n = 0; n < NR; ++n) {
      const size_t row = M0 + wr + m * 16 + rb;
      const int col = N0 + wc + n * 16 + fr;
      if (Cb != nullptr) {
#pragma unroll
        for (int r = 0; r < 4; ++r)
          Cb[(row + r) * N + col] = __float2bfloat16(acc[m][n][r]);
      } else {
        const float bb = bias[col];
#pragma unroll
        for (int r = 0; r < 4; ++r)
          Cf[(row + r) * N + col] = acc[m][n][r] + bb;
      }
    }
  }
}

// ---------------- depthwise conv, NCHW planes, LDS-staged ----------------
template <int KS>
__global__ __launch_bounds__(256) void k_dwconv_img(const bf16* __restrict__ in,
                                                    const float* __restrict__ w,
                                                    bf16* __restrict__ out) {
  constexpr int P = KS / 2;
  constexpr int ROWS = 64 + 2 * P;
  constexpr int PITCH = 80;
  constexpr int NCHUNK = ROWS * PITCH * 2 / 16;
  __shared__ __align__(16) bf16 pl[ROWS * PITCH];
  const int t = threadIdx.x;
  const int c = blockIdx.x, b = blockIdx.y;
  const bf16* __restrict__ ip = in + ((size_t)b * 768 + c) * 4096;
  bf16* __restrict__ op = out + ((size_t)b * 768 + c) * 4096;

  u32x4* pl4 = reinterpret_cast<u32x4*>(pl);
  for (int i = t; i < NCHUNK; i += 256) pl4[i] = u32x4{0, 0, 0, 0};
  __syncthreads();
  for (int q = t; q < 512; q += 256) {
    const int px0 = q * 8;
    const int y = px0 >> 6, x = px0 & 63;
    u32x4 v = *reinterpret_cast<const u32x4*>(ip + px0);
    *reinterpret_cast<u32x4*>(&pl[(y + P) * PITCH + 8 + x]) = v;
  }
  __syncthreads();

  float wk[KS * KS];
#pragma unroll
  for (int i = 0; i < KS * KS; ++i) wk[i] = w[c * KS * KS + i];

  const int x = t & 63;
  const int y0 = (t >> 6) * 16;
  float win[KS][KS];
#pragma unroll
  for (int r = 0; r < 2 * P; ++r)
#pragma unroll
    for (int kx = 0; kx < KS; ++kx)
      win[r % KS][kx] = __bfloat162float(pl[(y0 + r) * PITCH + 8 + x - P + kx]);
#pragma unroll
  for (int yy = 0; yy < 16; ++yy) {
    constexpr int twoP = 2 * P;
#pragma unroll
    for (int kx = 0; kx < KS; ++kx)
      win[(yy + twoP) % KS][kx] =
          __bfloat162float(pl[(y0 + yy + twoP) * PITCH + 8 + x - P + kx]);
    float acc = 0.f;
#pragma unroll
    for (int ky = 0; ky < KS; ++ky)
#pragma unroll
      for (int kx = 0; kx < KS; ++kx)
        acc += win[(yy + ky) % KS][kx] * wk[ky * KS + kx];
    op[(y0 + yy) * 64 + x] = __float2bfloat16(acc);
  }
}

// ---------------- chunked flash attention (swapped-QK^T, QBLK=64) ----------------
__global__ __launch_bounds__(256) void k_attn(const bf16* __restrict__ msq,
                                              bf16* __restrict__ out) {
  const int qt = blockIdx.x;
  const int combo = blockIdx.y;
  const int b = combo >> 4;
  const int h = (combo >> 1) & 7;
  const int ck = combo & 1;
  const int tid = threadIdx.x, lane = tid & 63, wv = tid >> 6;
  const int fr = lane & 15, hi = lane >> 4, fo = hi * 8;
  const size_t base = (size_t)b * 4096 * 768;
  const int n0 = ck * 2048 + qt * 64;

  __shared__ __align__(16) bf16 Kl[2][64][40];
  __shared__ __align__(16) bf16 Vt[2][32][72];
  __shared__ __align__(16) bf16 Pl[4][16][72];

  const float scale = 0.17677669529663687f;
  bf16x8 qf;
  {
    const int qrow = n0 + wv * 16 + fr;
    const bf16x8 v =
        *reinterpret_cast<const bf16x8*>(msq + base + (size_t)qrow * 768 + h * 32 + fo);
#pragma unroll
    for (int j = 0; j < 8; ++j) qf[j] = (__bf16)((float)v[j] * scale);
  }

  f32x4 oacc[2] = {};
  float mrun = 0.f, lrun = 0.f;
  const int sr = tid >> 2, sdc = (tid & 3) << 3;
  const int vswz = (tid & 3) << 4;

  u32x4 kr, vr;
  auto gload = [&](int kt) {
    const size_t rbase = base + (size_t)(ck * 2048 + kt * 64 + sr) * 768 + h * 32;
    kr = *reinterpret_cast<const u32x4*>(msq + rbase + 256 + sdc);
    vr = *reinterpret_cast<const u32x4*>(msq + rbase + 512 + sdc);
  };
  auto lwrite = [&](int buf) {
    *reinterpret_cast<u32x4*>(&Kl[buf][sr][sdc]) = kr;
    const bf16* vp = reinterpret_cast<const bf16*>(&vr);
#pragma unroll
    for (int j = 0; j < 8; ++j) Vt[buf][sdc + j][sr ^ vswz] = vp[j];
  };

  gload(0);
  lwrite(0);
  int cur = 0;
  for (int kt = 0; kt < 32; ++kt) {
    __syncthreads();
    if (kt + 1 < 32) gload(kt + 1);

    f32x4 sacc[4];
    __builtin_amdgcn_s_setprio(1);
#pragma unroll
    for (int j = 0; j < 4; ++j) {
      const bf16x8 kf = *reinterpret_cast<const bf16x8*>(&Kl[cur][j * 16 + fr][fo]);
      const f32x4 z = {0.f, 0.f, 0.f, 0.f};
      sacc[j] = __builtin_amdgcn_mfma_f32_16x16x32_bf16(kf, qf, z, 0, 0, 0);
    }
    __builtin_amdgcn_s_setprio(0);
    float mx = -1e30f;
#pragma unroll
    for (int j = 0; j < 4; ++j)
#pragma unroll
      for (int r = 0; r < 4; ++r) mx = fmaxf(mx, sacc[j][r]);
    mx = fmaxf(mx, __shfl_xor(mx, 16));
    mx = fmaxf(mx, __shfl_xor(mx, 32));
    if (!__all(mx <= mrun + 8.f)) {
      const float mnew = fmaxf(mrun, mx);
      const float corr = __expf(mrun - mnew);
      mrun = mnew;
      lrun *= corr;
#pragma unroll
      for (int r = 0; r < 4; ++r) {
        const float cf = __shfl(corr, hi * 4 + r);
        oacc[0][r] *= cf;
        oacc[1][r] *= cf;
      }
    }
    float sm = 0.f;
#pragma unroll
    for (int j = 0; j < 4; ++j) {
      bf16x4v pk;
#pragma unroll
      for (int r = 0; r < 4; ++r) {
        const float pz = __expf(sacc[j][r] - mrun);
        sm += pz;
        pk[r] = (__bf16)pz;
      }
      *reinterpret_cast<bf16x4v*>(&Pl[wv][fr][j * 16 + hi * 4]) = pk;
    }
    sm += __shfl_xor(sm, 16);
    sm += __shfl_xor(sm, 32);
    lrun += sm;

    __builtin_amdgcn_s_setprio(1);
#pragma unroll
    for (int kk = 0; kk < 2; ++kk) {
      const bf16x8 pa = *reinterpret_cast<const bf16x8*>(&Pl[wv][fr][kk * 32 + fo]);
#pragma unroll
      for (int nb = 0; nb < 2; ++nb) {
        const int d = nb * 16 + fr;
        const int colb = (kk * 32 + fo) ^ (((d >> 3) & 3) << 4);
        const bf16x8 vb = *reinterpret_cast<const bf16x8*>(&Vt[cur][d][colb]);
        oacc[nb] = __builtin_amdgcn_mfma_f32_16x16x32_bf16(pa, vb, oacc[nb], 0, 0, 0);
      }
    }
    __builtin_amdgcn_s_setprio(0);

    if (kt + 1 < 32) lwrite(cur ^ 1);
    cur ^= 1;
  }

#pragma unroll
  for (int r = 0; r < 4; ++r) {
    const float lf = __shfl(lrun, hi * 4 + r);
    const float inv = 1.f / lf;
    const int row = n0 + wv * 16 + hi * 4 + r;
#pragma unroll
    for (int nb = 0; nb < 2; ++nb)
      out[((size_t)b * 4096 + row) * 256 + h * 32 + nb * 16 + fr] =
          __float2bfloat16(oacc[nb][r] * inv);
  }
}

// ---------------- launcher ----------------
extern "C" void kernel_launch(void* const* d_in, const int* in_sizes, int n_in,
                              void* d_out, int out_size, void* d_ws, size_t ws_size,
                              hipStream_t stream) {
  (void)in_sizes; (void)n_in; (void)out_size; (void)ws_size;
  const float* x    = (const float*)d_in[0];
  const float* wrd  = (const float*)d_in[1];
  const float* wqkv = (const float*)d_in[2];
  const float* dw0  = (const float*)d_in[3];
  const float* pw0  = (const float*)d_in[4];
  const float* dw1  = (const float*)d_in[5];
  const float* pw1  = (const float*)d_in[6];
  const float* dw2  = (const float*)d_in[7];
  const float* pw2  = (const float*)d_in[8];
  const float* wrd2 = (const float*)d_in[9];
  const float* wprj = (const float*)d_in[10];
  const float* bprj = (const float*)d_in[11];
  float* out = (float*)d_out;

  char* p = (char*)d_ws;
  auto nxt = [&](size_t bytes) {
    char* r = p;
    p += (bytes + 255) & ~(size_t)255;
    return (bf16*)r;
  };
  bf16* xb   = nxt(8192ull * 512 * 2);
  bf16* w12T = nxt(768ull * 512 * 2);
  bf16* wrdB = nxt(512ull * 256 * 2);
  bf16* wqT  = nxt(768ull * 256 * 2);
  bf16* wr2T = nxt(768ull * 3072 * 2);
  bf16* wpT  = nxt(512ull * 256 * 2);
  bf16* qkv  = nxt(8192ull * 768 * 2);
  bf16* dtmp = nxt(8192ull * 768 * 2);
  bf16* y0   = nxt(8192ull * 768 * 2);
  bf16* y1   = nxt(8192ull * 768 * 2);
  bf16* y2   = nxt(8192ull * 768 * 2);
  bf16* msq  = nxt(8192ull * 768 * 2);
  bf16* qkvT = msq;  // NCHW qkv; dead before GEMM3 writes msq
  bf16* ao   = nxt(8192ull * 256 * 2);

  // prep: convert x; build fused weights via MFMA GEMM; transposed weights
  k_cvt_bf16<<<(8192 * 512 / 4) / 256, 256, 0, stream>>>(x, xb);
  k_cvt_bf16<<<(512 * 256 / 4) / 256, 256, 0, stream>>>(wrd, wrdB);
  k_transpose_bf16<<<dim3(8, 24), 256, 0, stream>>>(wqkv, wqT, 256, 768);
  // w12T[768][512] = wqT[768][256] @ wrdB[512][256]^T
  k_gemm_bt<64, 64><<<dim3(12, 8), 256, 0, stream>>>(wqT, wqT, wqT, wqT, wrdB, w12T,
                                                     nullptr, nullptr, 512, 256, 256,
                                                     1 << 20);
  k_transpose_bf16<<<dim3(24, 24), 256, 0, stream>>>(wrd2, wr2T, 3072, 768);
  k_fuse_pw<<<dim3(24, 12, 3), 256, 0, stream>>>(pw0, pw1, pw2, wrd2, wr2T);
  k_transpose_bf16<<<dim3(256 / 32, 512 / 32), 256, 0, stream>>>(wprj, wpT, 256, 512);

  // fused GEMM1+2: qkv = x @ w12   (M=8192 N=768 K=512)
  k_gemm_bt<64, 64><<<dim3(128, 12), 256, 0, stream>>>(xb, xb, xb, xb, w12T, qkv, nullptr,
                                                       nullptr, 768, 512, 512, 1 << 20);

  // qkv [2][4096][768] -> qkvT [2][768][4096]
  k_transpose2d<<<dim3(12, 64, 2), 256, 0, stream>>>(qkv, qkvT, 4096, 768);

  // conv branches: dw (NCHW) -> transpose to token-major (pw folded into GEMM3)
  k_dwconv_img<3><<<dim3(768, 2), 256, 0, stream>>>(qkvT, dw0, dtmp);
  k_transpose2d<<<dim3(64, 12, 2), 256, 0, stream>>>(dtmp, y0, 768, 4096);
  k_dwconv_img<5><<<dim3(768, 2), 256, 0, stream>>>(qkvT, dw1, dtmp);
  k_transpose2d<<<dim3(64, 12, 2), 256, 0, stream>>>(dtmp, y1, 768, 4096);
  k_dwconv_img<7><<<dim3(768, 2), 256, 0, stream>>>(qkvT, dw2, dtmp);
  k_transpose2d<<<dim3(64, 12, 2), 256, 0, stream>>>(dtmp, y2, 768, 4096);

  // GEMM3: msq = [qkv|d0|d1|d2] @ wr2T_fused  (K=3072 via 4 sources)
  k_gemm_bt<64, 64><<<dim3(128, 12), 256, 0, stream>>>(qkv, y0, y1, y2, wr2T, msq, nullptr,
                                                       nullptr, 768, 3072, 768, 12);

  // attention (64-row q-tiles, 4 blocks/CU)
  k_attn<<<dim3(32, 32), 256, 0, stream>>>(msq, ao);

  // GEMM4: out = ao @ w_proj + b_proj
  k_gemm_bt<64, 64><<<dim3(128, 8), 256, 0, stream>>>(ao, ao, ao, ao, wpT, nullptr, out,
                                                      bprj, 512, 256, 256, 1 << 20);
}